// Round 13
// baseline (124.316 us; speedup 1.0000x reference)
//
#include <hip/hip_runtime.h>

#define NS 512
#define DM 512
#define NH 8
#define DH 64
#define NHDH 512
#define ATTN_SIZE (2 * NH * NS * NS)  // 4194304
#define SMEM_BYTES 26112              // phase1: As[32][136]+Bs[64][136] f16
#define NBLK 512

typedef __attribute__((ext_vector_type(8))) _Float16 half8;
typedef __attribute__((ext_vector_type(4))) float f32x4;
typedef _Float16 h2 __attribute__((ext_vector_type(2)));
typedef unsigned short ushort_t;
typedef __attribute__((ext_vector_type(2))) unsigned uint2v;

#if defined(__has_builtin)
#if __has_builtin(__builtin_amdgcn_fdot2)
#define HAVE_FDOT2 1
#endif
#if __has_builtin(__builtin_amdgcn_cvt_pkrtz)
#define HAVE_PKRTZ 1
#endif
#endif

__device__ __forceinline__ unsigned pkh(float a, float b) {
#ifdef HAVE_PKRTZ
    auto r = __builtin_amdgcn_cvt_pkrtz(a, b);   // __fp16 ext_vector(2)
    return __builtin_bit_cast(unsigned, r);
#else
    h2 r; r[0] = (_Float16)a; r[1] = (_Float16)b;
    return __builtin_bit_cast(unsigned, r);
#endif
}

__device__ __forceinline__ float qdot2(unsigned w2, unsigned x2, float acc) {
#ifdef HAVE_FDOT2
    return __builtin_amdgcn_fdot2(__builtin_bit_cast(h2, w2),
                                  __builtin_bit_cast(h2, x2), acc, false);
#else
    h2 a = __builtin_bit_cast(h2, w2);
    h2 b = __builtin_bit_cast(h2, x2);
    return acc + (float)a[0] * (float)b[0] + (float)a[1] * (float)b[1];
#endif
}

__device__ __forceinline__ float dotabs(unsigned w2, unsigned q2, unsigned k2, float acc) {
    h2 s = __builtin_bit_cast(h2, q2) + __builtin_bit_cast(h2, k2);  // v_pk_add_f16
    unsigned a = __builtin_bit_cast(unsigned, s) & 0x7FFF7FFFu;      // packed |.|
    return qdot2(w2, a, acc);                                        // v_dot2_f32_f16
}

// ---------------------------------------------------------------------------
// Flag-based grid barrier: ZERO same-address RMWs (R12's 1024-deep fetch_add
// chain at ~200cy each = ~85us was the entire overhead). Arrival = parallel
// stores to 512 distinct flags; block 0 aggregates with 256 threads; departure
// = one flag line, read-only polling. Self-resetting for graph replay.
// Co-residency guaranteed: LDS 26112B -> 6 blk/CU; launch_bounds(256,2) caps
// VGPR at 256 -> >=2 blk/CU -> all 512 resident.
// ---------------------------------------------------------------------------
__device__ unsigned g_flags[NBLK];   // zero-initialized (.bss)
__device__ unsigned g_depart;

__device__ __forceinline__ void grid_barrier(int bid, int tid) {
    __syncthreads();
    if (tid == 0) {
        __threadfence();   // release phase-1 stores (agent scope)
        __hip_atomic_store(&g_flags[bid], 1u,
                           __ATOMIC_RELEASE, __HIP_MEMORY_SCOPE_AGENT);
    }
    if (bid == 0) {
        for (;;) {
            unsigned a = __hip_atomic_load(&g_flags[2 * tid],
                             __ATOMIC_ACQUIRE, __HIP_MEMORY_SCOPE_AGENT);
            unsigned b = __hip_atomic_load(&g_flags[2 * tid + 1],
                             __ATOMIC_ACQUIRE, __HIP_MEMORY_SCOPE_AGENT);
            if (__syncthreads_and((int)(a & b))) break;
            __builtin_amdgcn_s_sleep(2);
        }
        if (tid == 0) {
            __threadfence();
            __hip_atomic_store(&g_depart, 1u,
                               __ATOMIC_RELEASE, __HIP_MEMORY_SCOPE_AGENT);
        }
    }
    if (tid == 0) {
        while (__hip_atomic_load(&g_depart,
                   __ATOMIC_ACQUIRE, __HIP_MEMORY_SCOPE_AGENT) == 0u)
            __builtin_amdgcn_s_sleep(2);
        // reset own flag for the next graph replay
        __hip_atomic_store(&g_flags[bid], 0u,
                           __ATOMIC_RELAXED, __HIP_MEMORY_SCOPE_AGENT);
        __threadfence();
    }
    __syncthreads();
}

// Block 0 only, after phase 2: wait for all flags back to 0, clear g_depart.
__device__ __forceinline__ void grid_barrier_cleanup(int bid, int tid) {
    if (bid != 0) return;
    __syncthreads();
    for (;;) {
        unsigned a = __hip_atomic_load(&g_flags[2 * tid],
                         __ATOMIC_ACQUIRE, __HIP_MEMORY_SCOPE_AGENT);
        unsigned b = __hip_atomic_load(&g_flags[2 * tid + 1],
                         __ATOMIC_ACQUIRE, __HIP_MEMORY_SCOPE_AGENT);
        if (__syncthreads_and((int)((a | b) == 0u))) break;
        __builtin_amdgcn_s_sleep(2);
    }
    if (tid == 0)
        __hip_atomic_store(&g_depart, 0u,
                           __ATOMIC_RELEASE, __HIP_MEMORY_SCOPE_AGENT);
}

// ---------------------------------------------------------------------------
// Phase 1: fused convert+proj (unchanged from R12).
// ---------------------------------------------------------------------------
__device__ __forceinline__ void phase_proj(int bid, int tid,
    const float* __restrict__ query,
    const float* __restrict__ Wq, const float* __restrict__ bq,
    const float* __restrict__ Wk, const float* __restrict__ bk,
    ushort_t* __restrict__ qh, ushort_t* __restrict__ kh,
    float* __restrict__ kout, char* smem)
{
    const int h   = bid & 7;
    const int byt = (bid >> 3) & 31;
    const int bz  = bid >> 8;
    const float* __restrict__ W   = bz ? Wk : Wq;
    const float* __restrict__ bia = bz ? bk : bq;
    ushort_t* __restrict__ hout = bz ? kh : qh;

    ushort_t (*As)[136] = (ushort_t(*)[136])smem;                    // 32 rows
    ushort_t (*Bs)[136] = (ushort_t(*)[136])(smem + 32 * 136 * 2);   // 64 rows

    const int lane = tid & 63;
    const int w4   = tid >> 6;
    const int wr   = w4 >> 1, wc = w4 & 1;
    const int l15  = lane & 15, l4 = lane >> 4;

    float4 af[2][2];
    float  bf[8][4];
    #pragma unroll
    for (int i = 0; i < 2; ++i) {
        int s = i * 256 + tid;
        const float* src = query + (size_t)(byt * 32 + (s >> 4)) * DM + (s & 15) * 8;
        af[i][0] = *(const float4*)(src);
        af[i][1] = *(const float4*)(src + 4);
    }
    #pragma unroll
    for (int p = 0; p < 8; ++p)
        #pragma unroll
        for (int j = 0; j < 4; ++j)
            bf[p][j] = W[(size_t)(p * 16 + w4 * 4 + j) * NHDH + h * 64 + lane];

    f32x4 acc[2];
    acc[0] = (f32x4){0.f, 0.f, 0.f, 0.f};
    acc[1] = (f32x4){0.f, 0.f, 0.f, 0.f};

    for (int kc = 0; kc < 4; ++kc) {
        __syncthreads();
        #pragma unroll
        for (int i = 0; i < 2; ++i) {
            int s = i * 256 + tid;
            uint4 pk;
            pk.x = pkh(af[i][0].x, af[i][0].y);
            pk.y = pkh(af[i][0].z, af[i][0].w);
            pk.z = pkh(af[i][1].x, af[i][1].y);
            pk.w = pkh(af[i][1].z, af[i][1].w);
            *(uint4*)&As[s >> 4][(s & 15) * 8] = pk;
        }
        #pragma unroll
        for (int p = 0; p < 8; ++p) {
            uint2v pk;
            pk.x = pkh(bf[p][0], bf[p][1]);
            pk.y = pkh(bf[p][2], bf[p][3]);
            *(uint2v*)&Bs[lane][p * 16 + w4 * 4] = pk;
        }
        __syncthreads();
        if (kc < 3) {
            #pragma unroll
            for (int i = 0; i < 2; ++i) {
                int s = i * 256 + tid;
                const float* src = query + (size_t)(byt * 32 + (s >> 4)) * DM
                                 + (kc + 1) * 128 + (s & 15) * 8;
                af[i][0] = *(const float4*)(src);
                af[i][1] = *(const float4*)(src + 4);
            }
            #pragma unroll
            for (int p = 0; p < 8; ++p)
                #pragma unroll
                for (int j = 0; j < 4; ++j)
                    bf[p][j] = W[(size_t)((kc + 1) * 128 + p * 16 + w4 * 4 + j) * NHDH
                                 + h * 64 + lane];
        }
        #pragma unroll
        for (int ks = 0; ks < 4; ++ks) {
            half8 a0 = *(const half8*)&As[wr * 16 + l15     ][ks * 32 + l4 * 8];
            half8 b0 = *(const half8*)&Bs[wc * 32 + l15     ][ks * 32 + l4 * 8];
            half8 b1 = *(const half8*)&Bs[wc * 32 + 16 + l15][ks * 32 + l4 * 8];
            acc[0] = __builtin_amdgcn_mfma_f32_16x16x32_f16(a0, b0, acc[0], 0, 0, 0);
            acc[1] = __builtin_amdgcn_mfma_f32_16x16x32_f16(a0, b1, acc[1], 0, 0, 0);
        }
    }

    #pragma unroll
    for (int g = 0; g < 2; ++g) {
        const float bg = bia[h * 64 + wc * 32 + g * 16 + l15];
        #pragma unroll
        for (int j = 0; j < 4; ++j) {
            int rt = wr * 16 + l4 * 4 + j;
            int ct = wc * 32 + g * 16 + l15;
            int rg = byt * 32 + rt;
            int ns_ = rg >> 1, b_ = rg & 1;
            size_t idx = ((size_t)(b_ * NH + h) * NS + ns_) * DH + ct;
            float vv = acc[g][j] + bg;
            if (bz) kout[idx] = vv;
            _Float16 hv = (_Float16)vv;
            hout[idx] = __builtin_bit_cast(ushort_t, hv);
        }
    }
}

// ---------------------------------------------------------------------------
// Phase 2: attn, named scalars (unchanged from R12).
// ---------------------------------------------------------------------------
#define REP16L(M) M(0) M(1) M(2) M(3) M(4) M(5) M(6) M(7) M(8) M(9) M(10) M(11) M(12) M(13) M(14) M(15)
#define REP16H(M) M(16) M(17) M(18) M(19) M(20) M(21) M(22) M(23) M(24) M(25) M(26) M(27) M(28) M(29) M(30) M(31)
#define REP32(M) REP16L(M) REP16H(M)

#define DECLK(p) unsigned KA##p, KB##p;
#define DECLQ(p) unsigned Q##p;
#define DECLW(p) unsigned WP##p;

#define LOAD4(t0, t1, t2, t3, src) { uint4 t_ = *(const uint4*)(src); t0 = t_.x; t1 = t_.y; t2 = t_.z; t3 = t_.w; }

#define WLOAD(j, A, B) { float4 v_ = *(const float4*)(wrow + 4 * (j)); \
    A = (unsigned)__builtin_amdgcn_readfirstlane((int)pkh(v_.x, v_.y)); \
    B = (unsigned)__builtin_amdgcn_readfirstlane((int)pkh(v_.z, v_.w)); }

#define KDT(p) kd0 = qdot2(WP##p, KA##p, kd0); kd1 = qdot2(WP##p, KB##p, kd1);
#define QDL(p) qd0 = qdot2(WP##p, Q##p, qd0);
#define QDH(p) qd1 = qdot2(WP##p, Q##p, qd1);
#define ABT(p) a0 = dotabs(WP##p, Q##p, KA##p, a0); a1 = dotabs(WP##p, Q##p, KB##p, a1);

__device__ __forceinline__ void phase_attn(int bid, int tid,
    const ushort_t* __restrict__ qh, const ushort_t* __restrict__ kh,
    const float* __restrict__ w, float* __restrict__ attn, char* smem)
{
    ushort_t (*Qs)[72] = (ushort_t(*)[72])smem;   // 64 x 72 = 9216 B

    const int lane = tid & 63;
    const int wv   = tid >> 6;
    const int kb   = bid & 3;
    const int bh   = (bid >> 2) & 15;
    const int qg   = bid >> 6;          // 0..7
    const int h    = bh & 7;

    const int c0 = kb * 128 + lane;
    const ushort_t* kb0 = kh + (size_t)bh * NS * DH + (size_t)c0 * DH;
    const ushort_t* kb1 = kb0 + 64 * DH;

    REP32(DECLK)
    LOAD4(KA0,  KA1,  KA2,  KA3,  kb0 + 0)
    LOAD4(KA4,  KA5,  KA6,  KA7,  kb0 + 8)
    LOAD4(KA8,  KA9,  KA10, KA11, kb0 + 16)
    LOAD4(KA12, KA13, KA14, KA15, kb0 + 24)
    LOAD4(KA16, KA17, KA18, KA19, kb0 + 32)
    LOAD4(KA20, KA21, KA22, KA23, kb0 + 40)
    LOAD4(KA24, KA25, KA26, KA27, kb0 + 48)
    LOAD4(KA28, KA29, KA30, KA31, kb0 + 56)
    LOAD4(KB0,  KB1,  KB2,  KB3,  kb1 + 0)
    LOAD4(KB4,  KB5,  KB6,  KB7,  kb1 + 8)
    LOAD4(KB8,  KB9,  KB10, KB11, kb1 + 16)
    LOAD4(KB12, KB13, KB14, KB15, kb1 + 24)
    LOAD4(KB16, KB17, KB18, KB19, kb1 + 32)
    LOAD4(KB20, KB21, KB22, KB23, kb1 + 40)
    LOAD4(KB24, KB25, KB26, KB27, kb1 + 48)
    LOAD4(KB28, KB29, KB30, KB31, kb1 + 56)

    {
        const uint4* qsrc = (const uint4*)(qh + (size_t)bh * NS * DH + (size_t)qg * 64 * DH);
        #pragma unroll
        for (int i = 0; i < 2; ++i) {
            int s = i * 256 + tid;
            *(uint4*)&Qs[s >> 3][(s & 7) * 8] = qsrc[s];
        }
    }

    const float* wrow = w + h * DH;
    REP32(DECLW)
    WLOAD(0,  WP0,  WP1)  WLOAD(1,  WP2,  WP3)  WLOAD(2,  WP4,  WP5)  WLOAD(3,  WP6,  WP7)
    WLOAD(4,  WP8,  WP9)  WLOAD(5,  WP10, WP11) WLOAD(6,  WP12, WP13) WLOAD(7,  WP14, WP15)
    WLOAD(8,  WP16, WP17) WLOAD(9,  WP18, WP19) WLOAD(10, WP20, WP21) WLOAD(11, WP22, WP23)
    WLOAD(12, WP24, WP25) WLOAD(13, WP26, WP27) WLOAD(14, WP28, WP29) WLOAD(15, WP30, WP31)

    float kd0 = 0.f, kd1 = 0.f;
    REP32(KDT)

    __syncthreads();

    for (int t = 0; t < 2; ++t) {
        float* obase = attn + (size_t)bh * NS * NS
                     + (size_t)(qg * 64 + t * 32 + wv * 8) * NS + c0;
        for (int r = 0; r < 8; ++r) {
            const int row = t * 32 + wv * 8 + r;
            REP32(DECLQ)
            LOAD4(Q0,  Q1,  Q2,  Q3,  &Qs[row][0])
            LOAD4(Q4,  Q5,  Q6,  Q7,  &Qs[row][8])
            LOAD4(Q8,  Q9,  Q10, Q11, &Qs[row][16])
            LOAD4(Q12, Q13, Q14, Q15, &Qs[row][24])
            LOAD4(Q16, Q17, Q18, Q19, &Qs[row][32])
            LOAD4(Q20, Q21, Q22, Q23, &Qs[row][40])
            LOAD4(Q24, Q25, Q26, Q27, &Qs[row][48])
            LOAD4(Q28, Q29, Q30, Q31, &Qs[row][56])

            float qd0 = 0.f, qd1 = 0.f;
            REP16L(QDL)
            REP16H(QDH)
            const float qd = qd0 + qd1;

            float a0 = 0.f, a1 = 0.f;
            REP32(ABT)

            float* ob = obase + r * NS;
            ob[0]  = fmaf(0.495f, a0, 0.505f * (qd + kd0));
            ob[64] = fmaf(0.495f, a1, 0.505f * (qd + kd1));
        }
    }
}

// ======================= single fused kernel =======================
__global__ __launch_bounds__(256, 2) void fused5(
    const float* __restrict__ query,
    const float* __restrict__ Wq, const float* __restrict__ bq,
    const float* __restrict__ Wk, const float* __restrict__ bk,
    const float* __restrict__ w,
    ushort_t* __restrict__ qh, ushort_t* __restrict__ kh,
    float* __restrict__ kout, float* __restrict__ attn)
{
    __shared__ __align__(16) char smem[SMEM_BYTES];
    const int bid = blockIdx.x, tid = threadIdx.x;

    phase_proj(bid, tid, query, Wq, bq, Wk, bk, qh, kh, kout, smem);
    grid_barrier(bid, tid);
    phase_attn(bid, tid, qh, kh, w, attn, smem);
    grid_barrier_cleanup(bid, tid);
}

extern "C" void kernel_launch(void* const* d_in, const int* in_sizes, int n_in,
                              void* d_out, int out_size, void* d_ws, size_t ws_size,
                              hipStream_t stream) {
    const float* query = (const float*)d_in[0];
    const float* Wq    = (const float*)d_in[1];
    const float* bq    = (const float*)d_in[2];
    const float* Wk    = (const float*)d_in[3];
    const float* bk    = (const float*)d_in[4];
    const float* w     = (const float*)d_in[5];

    float* attn = (float*)d_out;
    float* kout = (float*)d_out + ATTN_SIZE;     // k-proj f32 == output 2

    char* ws = (char*)d_ws;
    ushort_t* qh = (ushort_t*)(ws);              // 1 MB f16 q-proj
    ushort_t* kh = (ushort_t*)(ws + (1u << 20)); // 1 MB f16 k-proj

    fused5<<<dim3(NBLK), dim3(256), 0, stream>>>(query, Wq, bq, Wk, bk, w,
                                                 qh, kh, kout, attn);
}

// Round 14
// 47.450 us; speedup vs baseline: 2.6199x; 2.6199x over previous
//
#include <hip/hip_runtime.h>

#define NS 512
#define DM 512
#define NH 8
#define DH 64
#define NHDH 512
#define ATTN_SIZE (2 * NH * NS * NS)  // 4194304

typedef __attribute__((ext_vector_type(8))) _Float16 half8;
typedef __attribute__((ext_vector_type(4))) float f32x4;
typedef _Float16 h2 __attribute__((ext_vector_type(2)));
typedef unsigned short ushort_t;
typedef __attribute__((ext_vector_type(2))) unsigned uint2v;

#if defined(__has_builtin)
#if __has_builtin(__builtin_amdgcn_fdot2)
#define HAVE_FDOT2 1
#endif
#if __has_builtin(__builtin_amdgcn_cvt_pkrtz)
#define HAVE_PKRTZ 1
#endif
#endif

__device__ __forceinline__ unsigned pkh(float a, float b) {
#ifdef HAVE_PKRTZ
    auto r = __builtin_amdgcn_cvt_pkrtz(a, b);   // __fp16 ext_vector(2)
    return __builtin_bit_cast(unsigned, r);
#else
    h2 r; r[0] = (_Float16)a; r[1] = (_Float16)b;
    return __builtin_bit_cast(unsigned, r);
#endif
}

__device__ __forceinline__ float qdot2(unsigned w2, unsigned x2, float acc) {
#ifdef HAVE_FDOT2
    return __builtin_amdgcn_fdot2(__builtin_bit_cast(h2, w2),
                                  __builtin_bit_cast(h2, x2), acc, false);
#else
    h2 a = __builtin_bit_cast(h2, w2);
    h2 b = __builtin_bit_cast(h2, x2);
    return acc + (float)a[0] * (float)b[0] + (float)a[1] * (float)b[1];
#endif
}

__device__ __forceinline__ float dotabs(unsigned w2, unsigned q2, unsigned k2, float acc) {
    h2 s = __builtin_bit_cast(h2, q2) + __builtin_bit_cast(h2, k2);  // v_pk_add_f16
    unsigned a = __builtin_bit_cast(unsigned, s) & 0x7FFF7FFFu;      // packed |.|
    return qdot2(w2, a, acc);                                        // v_dot2_f32_f16
}

// ---------------------------------------------------------------------------
// ONE kernel, NO grid barrier. 512 blocks = (kt:4) x (bh:16) x (qt:8).
// Each block redundantly computes the projections it needs (64 q-rows +
// 128 k-rows x one 64-col head, f16 MFMA) directly into LDS tiles, then runs
// the R9 attn core from LDS. Zero cross-block dependencies -> no fences, no
// coherence traffic, graph-replay safe. kout written by qt==0 blocks only.
// amdgpu_waves_per_eu(2,4) pins the register allocator to a 128-256 VGPR
// budget (the repeated VGPR=56 rematerialization trap came from an unbounded
// upper occupancy target).
// ---------------------------------------------------------------------------
__global__ __attribute__((amdgpu_flat_work_group_size(256, 256),
                          amdgpu_waves_per_eu(2, 4)))
void fused6(const float* __restrict__ query,
            const float* __restrict__ Wq, const float* __restrict__ bq,
            const float* __restrict__ Wk, const float* __restrict__ bk,
            const float* __restrict__ w,
            float* __restrict__ kout, float* __restrict__ attn)
{
    __shared__ __align__(16) char smem[34816];
    // phase A overlay: As[64][136] @0 (17408 B), Bs[64][136] @17408
    // phase B/C overlay: Qt[64][72] @0 (9216 B), Kt[128][72] @9216 (18432 B)
    ushort_t (*As)[136] = (ushort_t(*)[136])smem;
    ushort_t (*Bs)[136] = (ushort_t(*)[136])(smem + 17408);
    ushort_t (*Qt)[72]  = (ushort_t(*)[72])smem;
    ushort_t (*Kt)[72]  = (ushort_t(*)[72])(smem + 9216);

    const int tid  = threadIdx.x;
    const int bid  = blockIdx.x;
    const int kt   = bid & 3;          // 128 k-cols
    const int bh   = (bid >> 2) & 15;  // b*8+h
    const int qt   = bid >> 6;         // 0..7 (64 q-rows)
    const int b    = bh >> 3;
    const int h    = bh & 7;

    const int lane = tid & 63;
    const int w4   = tid >> 6;         // wave 0..3
    const int l15  = lane & 15, l4 = lane >> 4;

    // =================== Phase A: projections (f16 MFMA) ===================
    // groups: g0 = q-rows ns=qt*64+r ; g1 = k-rows ns=kt*128+r ; g2 = +64
    f32x4 acc[3][4];
    #pragma unroll
    for (int g = 0; g < 3; ++g)
        #pragma unroll
        for (int cf = 0; cf < 4; ++cf) acc[g][cf] = (f32x4){0.f, 0.f, 0.f, 0.f};

    const int nsb[3] = {qt * 64, kt * 128, kt * 128 + 64};

    for (int kc = 0; kc < 4; ++kc) {
        #pragma unroll
        for (int g = 0; g < 3; ++g) {
            __syncthreads();   // previous MFMA's As/Bs readers done
            if (g < 2) {
                // stage Bs = W^T slice [col=lane][k] for this kc (g0:Wq, g1:Wk)
                const float* __restrict__ W = g ? Wk : Wq;
                float bf[8][4];
                #pragma unroll
                for (int p = 0; p < 8; ++p)
                    #pragma unroll
                    for (int j = 0; j < 4; ++j)
                        bf[p][j] = W[(size_t)(kc * 128 + p * 16 + w4 * 4 + j) * NHDH
                                     + h * 64 + lane];
                #pragma unroll
                for (int p = 0; p < 8; ++p) {
                    uint2v pk;
                    pk.x = pkh(bf[p][0], bf[p][1]);
                    pk.y = pkh(bf[p][2], bf[p][3]);
                    *(uint2v*)&Bs[lane][p * 16 + w4 * 4] = pk;
                }
            }
            // stage As = query rows of group g (64 rows x 128 k), f32->f16
            {
                const int base = nsb[g];
                #pragma unroll
                for (int i = 0; i < 4; ++i) {
                    int s = i * 256 + tid;
                    int r = s >> 4, q8 = s & 15;
                    const float* src = query + (size_t)(2 * (base + r) + b) * DM
                                     + kc * 128 + q8 * 8;
                    float4 v0 = *(const float4*)(src);
                    float4 v1 = *(const float4*)(src + 4);
                    uint4 pk;
                    pk.x = pkh(v0.x, v0.y);
                    pk.y = pkh(v0.z, v0.w);
                    pk.z = pkh(v1.x, v1.y);
                    pk.w = pkh(v1.z, v1.w);
                    *(uint4*)&As[r][q8 * 8] = pk;
                }
            }
            __syncthreads();
            #pragma unroll
            for (int cf = 0; cf < 4; ++cf)
                #pragma unroll
                for (int ks = 0; ks < 4; ++ks) {
                    half8 a = *(const half8*)&As[w4 * 16 + l15][ks * 32 + l4 * 8];
                    half8 bb = *(const half8*)&Bs[cf * 16 + l15][ks * 32 + l4 * 8];
                    acc[g][cf] = __builtin_amdgcn_mfma_f32_16x16x32_f16(a, bb, acc[g][cf], 0, 0, 0);
                }
        }
    }

    // ============ Phase B: epilogue -> LDS tiles (+ kout for qt==0) ============
    __syncthreads();   // all MFMA reads of As/Bs done; overlay becomes Qt/Kt
    #pragma unroll
    for (int g = 0; g < 3; ++g) {
        const float* __restrict__ bia = g ? bk : bq;
        #pragma unroll
        for (int cf = 0; cf < 4; ++cf) {
            const int col = cf * 16 + l15;
            const float bg = bia[h * 64 + col];
            #pragma unroll
            for (int j = 0; j < 4; ++j) {
                const int row = w4 * 16 + l4 * 4 + j;
                float v = acc[g][cf][j] + bg;
                _Float16 hv = (_Float16)v;
                if (g == 0) {
                    Qt[row][col] = __builtin_bit_cast(ushort_t, hv);
                } else {
                    Kt[(g - 1) * 64 + row][col] = __builtin_bit_cast(ushort_t, hv);
                    if (qt == 0)
                        kout[((size_t)(b * NH + h) * NS + kt * 128 + (g - 1) * 64 + row) * DH + col] = v;
                }
            }
        }
    }
    __syncthreads();   // tiles visible to all waves

    // =================== Phase C: attn core (R9 structure) ===================
    // lane owns attn k-cols (kt*128 + lane) and (+64): K rows of Kt.
    __align__(16) unsigned kr0[32], kr1[32];
    #pragma unroll
    for (int i = 0; i < 8; ++i)
        *(uint4*)&kr0[i * 4] = *(const uint4*)&Kt[lane][i * 8];
    #pragma unroll
    for (int i = 0; i < 8; ++i)
        *(uint4*)&kr1[i * 4] = *(const uint4*)&Kt[64 + lane][i * 8];

    // scoring weights -> f16 pairs in SGPRs
    unsigned wp[32];
    const float* wrow = w + h * DH;
    #pragma unroll
    for (int i = 0; i < 16; ++i) {
        float4 v = *(const float4*)(wrow + i * 4);
        wp[2 * i]     = (unsigned)__builtin_amdgcn_readfirstlane((int)pkh(v.x, v.y));
        wp[2 * i + 1] = (unsigned)__builtin_amdgcn_readfirstlane((int)pkh(v.z, v.w));
    }

    float kd0 = 0.f, kd1 = 0.f;
    #pragma unroll
    for (int p = 0; p < 32; ++p) {
        kd0 = qdot2(wp[p], kr0[p], kd0);
        kd1 = qdot2(wp[p], kr1[p], kd1);
    }

    #pragma unroll
    for (int t = 0; t < 2; ++t) {
        float* obase = attn + (size_t)bh * NS * NS
                     + (size_t)(qt * 64 + t * 32 + w4 * 8) * NS + kt * 128 + lane;
        #pragma unroll 2
        for (int r = 0; r < 8; ++r) {
            const int row = t * 32 + w4 * 8 + r;
            __align__(16) unsigned q2a[32];
            #pragma unroll
            for (int i = 0; i < 8; ++i)
                *(uint4*)&q2a[i * 4] = *(const uint4*)&Qt[row][i * 8];

            float qd0 = 0.f, qd1 = 0.f;
            #pragma unroll
            for (int p = 0; p < 16; ++p) {
                qd0 = qdot2(wp[2 * p],     q2a[2 * p],     qd0);
                qd1 = qdot2(wp[2 * p + 1], q2a[2 * p + 1], qd1);
            }
            const float qd = qd0 + qd1;

            float a0 = 0.f, a1 = 0.f;
            #pragma unroll
            for (int p = 0; p < 32; ++p) {
                const unsigned q2 = q2a[p], w2 = wp[p];
                a0 = dotabs(w2, q2, kr0[p], a0);
                a1 = dotabs(w2, q2, kr1[p], a1);
            }

            float* ob = obase + r * NS;
            ob[0]  = fmaf(0.495f, a0, 0.505f * (qd + kd0));
            ob[64] = fmaf(0.495f, a1, 0.505f * (qd + kd1));
        }
    }
}

extern "C" void kernel_launch(void* const* d_in, const int* in_sizes, int n_in,
                              void* d_out, int out_size, void* d_ws, size_t ws_size,
                              hipStream_t stream) {
    const float* query = (const float*)d_in[0];
    const float* Wq    = (const float*)d_in[1];
    const float* bq    = (const float*)d_in[2];
    const float* Wk    = (const float*)d_in[3];
    const float* bk    = (const float*)d_in[4];
    const float* w     = (const float*)d_in[5];

    float* attn = (float*)d_out;
    float* kout = (float*)d_out + ATTN_SIZE;     // k-proj f32 == output 2

    fused6<<<dim3(512), dim3(256), 0, stream>>>(query, Wq, bq, Wk, bk, w,
                                                kout, attn);
}